// Round 7
// baseline (28.270 us; speedup 1.0000x reference)
//
#include <hip/hip_runtime.h>
#include <math.h>

// HungarianMatcher cost matrix:
//   C[i,j] = 5*L1(pred_box_i, tgt_box_j) + 2*(pos-neg focal at tgt class j) - 2*GIoU
// Shapes: pred_logits [BN,NC], pred_boxes [BN,4], tgt_ids [NT], tgt_bbox [NT,4]
// BN=16*900=14400, NC=91, NT=960. Output [BN,NT] fp32.
//
// R7: barrier-free wave-autonomous design. Each wave builds a PRIVATE copy of
// the 4-row focal class table in its own LDS slice (redundant work, but no
// s_barrier at all -> no block-wide convoy). Wave-internal visibility via
// s_waitcnt lgkmcnt(0) only.

#define ALPHA_F   0.25f
#define COST_CLS  2.0f
#define COST_BBOX 5.0f
#define COST_GIOU 2.0f
#define EPS_F     1e-8f

constexpr int THREADS = 256;

// ---------------------- specialized kernel (ROWS = 4) -----------------------
template<int NC, int NT>
__global__ __launch_bounds__(THREADS) void matcher_kernel_s(
    const float* __restrict__ logits,   // [BN, NC]
    const float* __restrict__ boxes,    // [BN, 4] cxcywh
    const int*   __restrict__ tids,     // [NT]
    const float* __restrict__ tboxes,   // [NT, 4] cxcywh
    float*       __restrict__ out)      // [BN, NT]
{
    constexpr int ROWS   = 4;
    constexpr int JPT    = 4;                 // contiguous targets per thread
    constexpr int NJT    = NT / JPT;          // 240 active threads
    constexpr int NTAB   = ROWS * NC;         // 364 table entries
    constexpr int NCP    = 96;                // padded class count
    constexpr int NWAVES = THREADS / 64;      // 4
    constexpr int CPW    = (NTAB + 63) / 64;  // 6 chains per lane (per-wave table)

    __shared__ float4 s_cls4[NWAVES * NCP];   // 4 private slices, 6 KB total

    const int tid  = threadIdx.x;
    const int wave = tid >> 6;
    const int lane = tid & 63;
    const int row0 = blockIdx.x * ROWS;
    const bool active = tid < NJT;

    float4* const s_wave4 = s_cls4 + wave * NCP;          // this wave's slice
    float*  const s_wavef = reinterpret_cast<float*>(s_wave4);

    // ---- issue logits loads for this wave's private table (coalesced) ----
    const float* __restrict__ lg = logits + (size_t)row0 * NC;
    float lv[CPW];
    #pragma unroll
    for (int i = 0; i < CPW; ++i) {
        const int t = lane + i * 64;
        lv[i] = (t < NTAB) ? lg[t] : 0.0f;
    }

    // ---- this thread's 4 targets: derived, row-invariant registers ----
    float tcx[JPT], tcy[JPT], tw[JPT], th[JPT];
    float tx0[JPT], tx1[JPT], ty0[JPT], ty1[JPT], tarea[JPT];
    int   ic[JPT];
    if (active) {
        const int4 tv = reinterpret_cast<const int4*>(tids)[tid];
        ic[0] = tv.x; ic[1] = tv.y; ic[2] = tv.z; ic[3] = tv.w;
        #pragma unroll
        for (int k = 0; k < JPT; ++k) {
            const float4 b = reinterpret_cast<const float4*>(tboxes)[tid * JPT + k];
            tcx[k] = b.x; tcy[k] = b.y; tw[k] = b.z; th[k] = b.w;
            const float hw = 0.5f * b.z, hh = 0.5f * b.w;
            tx0[k] = b.x - hw;  tx1[k] = b.x + hw;
            ty0[k] = b.y - hh;  ty1[k] = b.y + hh;
            tarea[k] = b.z * b.w;
        }
    } else {
        #pragma unroll
        for (int k = 0; k < JPT; ++k) {
            tcx[k]=tcy[k]=tw[k]=th[k]=tx0[k]=tx1[k]=ty0[k]=ty1[k]=tarea[k]=0.f;
            ic[k] = 0;
        }
    }

    // ---- per-wave focal class table, class-major: s_wavef[c*ROWS + r] ----
    #pragma unroll
    for (int i = 0; i < CPW; ++i) {
        const int t = lane + i * 64;
        if (t < NTAB) {
            const float x  = lv[i];
            const float p  = 1.0f / (1.0f + __expf(-x));
            const float om = 1.0f - p;
            const float neg = (1.0f - ALPHA_F) * p * p * (-__logf(om + EPS_F));
            const float pos = ALPHA_F * om * om        * (-__logf(p  + EPS_F));
            const int r = t / NC, c = t - r * NC;
            s_wavef[c * ROWS + r] = pos - neg;
        }
    }
    // wave-internal visibility: all this wave's ds_writes drained; LDS is
    // physically shared, so after lgkmcnt(0) every lane sees the full slice.
    // memory clobber stops the compiler moving the ds_reads above this point.
    asm volatile("s_waitcnt lgkmcnt(0)" ::: "memory");

    if (!active) return;

    // ---- prefetch the 16 class costs as 4x ds_read_b128 from our slice ----
    float4 cc[JPT];
    #pragma unroll
    for (int k = 0; k < JPT; ++k)
        cc[k] = s_wave4[ic[k]];

    // ---- pred boxes (uniform addresses -> scalar loads) ----
    float4 pbv[ROWS];
    #pragma unroll
    for (int r = 0; r < ROWS; ++r)
        pbv[r] = reinterpret_cast<const float4*>(boxes)[row0 + r];

    float* __restrict__ optr = out + (size_t)row0 * NT + tid * JPT;
    #pragma unroll
    for (int r = 0; r < ROWS; ++r) {
        const float4 pb = pbv[r];
        const float px0 = pb.x - 0.5f * pb.z, py0 = pb.y - 0.5f * pb.w;
        const float px1 = pb.x + 0.5f * pb.z, py1 = pb.y + 0.5f * pb.w;
        const float parea = pb.z * pb.w;

        float rv[JPT];
        #pragma unroll
        for (int k = 0; k < JPT; ++k) {
            // L1 in cxcywh space (abs folds into VOP3 src modifiers)
            const float l1 = (fabsf(pb.x - tcx[k]) + fabsf(pb.y - tcy[k]))
                           + (fabsf(pb.z - tw[k])  + fabsf(pb.w - th[k]));
            // raw intersection extents (feed enclosing box too)
            const float iwr = fminf(px1, tx1[k]) - fmaxf(px0, tx0[k]);
            const float ihr = fminf(py1, ty1[k]) - fmaxf(py0, ty0[k]);
            const float inter = fmaxf(iwr, 0.0f) * fmaxf(ihr, 0.0f);
            const float uni = (parea + tarea[k]) - inter;
            // enclosing box via identity: cw = pw + tw - iwr
            const float cw = (pb.z + tw[k]) - iwr;
            const float ch = (pb.w + th[k]) - ihr;
            const float carea = cw * ch;
            // giou = [carea*(inter-uni)+uni^2] / (uni*carea), one rcp
            const float num  = carea * (inter - uni) + uni * uni;
            const float giou = num * __builtin_amdgcn_rcpf(uni * carea);
            // class cost from the prefetched float4 (r compile-time)
            const float ccls = (r == 0) ? cc[k].x : (r == 1) ? cc[k].y
                             : (r == 2) ? cc[k].z : cc[k].w;
            rv[k] = (COST_BBOX * l1 + COST_CLS * ccls) - COST_GIOU * giou;
        }
        *reinterpret_cast<float4*>(optr) = make_float4(rv[0], rv[1], rv[2], rv[3]);
        optr += NT;
    }
}

// ----------------------------- generic fallback -----------------------------
constexpr int GROWS = 8;
__global__ __launch_bounds__(THREADS) void matcher_kernel_g(
    const float* __restrict__ logits, const float* __restrict__ boxes,
    const int* __restrict__ tids, const float* __restrict__ tboxes,
    float* __restrict__ out, int BN, int NC, int NT)
{
    extern __shared__ float s_cls_g[];
    const int tid  = threadIdx.x;
    const int row0 = blockIdx.x * GROWS;
    const int nrows = (BN - row0 < GROWS) ? (BN - row0) : GROWS;

    for (int t = tid; t < nrows * NC; t += THREADS) {
        const int r = t / NC, c = t - r * NC;
        const float x  = logits[(size_t)(row0 + r) * NC + c];
        const float p  = 1.0f / (1.0f + expf(-x));
        const float om = 1.0f - p;
        const float neg = (1.0f - ALPHA_F) * p * p * (-logf(om + EPS_F));
        const float pos = ALPHA_F * om * om        * (-logf(p + EPS_F));
        s_cls_g[r * NC + c] = pos - neg;
    }
    __syncthreads();

    for (int r = 0; r < nrows; ++r) {
        const int row = row0 + r;
        const float4 pb = reinterpret_cast<const float4*>(boxes)[row];
        const float px0 = pb.x - 0.5f * pb.z, py0 = pb.y - 0.5f * pb.w;
        const float px1 = pb.x + 0.5f * pb.z, py1 = pb.y + 0.5f * pb.w;
        const float parea = pb.z * pb.w;
        for (int j = tid; j < NT; j += THREADS) {
            const float4 b = reinterpret_cast<const float4*>(tboxes)[j];
            const float bx0 = b.x - 0.5f * b.z, by0 = b.y - 0.5f * b.w;
            const float bx1 = b.x + 0.5f * b.z, by1 = b.y + 0.5f * b.w;
            const float l1 = fabsf(pb.x - b.x) + fabsf(pb.y - b.y)
                           + fabsf(pb.z - b.z) + fabsf(pb.w - b.w);
            const float iw = fmaxf(fminf(px1, bx1) - fmaxf(px0, bx0), 0.0f);
            const float ih = fmaxf(fminf(py1, by1) - fmaxf(py0, by0), 0.0f);
            const float inter = iw * ih;
            const float uni = parea + b.z * b.w - inter;
            const float iou = inter / uni;
            const float cw = fmaxf(px1, bx1) - fminf(px0, bx0);
            const float ch = fmaxf(py1, by1) - fminf(py0, by0);
            const float carea = cw * ch;
            const float giou = iou - (carea - uni) / carea;
            const float ccls = s_cls_g[r * NC + tids[j]];
            out[(size_t)row * NT + j] = COST_BBOX * l1 + COST_CLS * ccls - COST_GIOU * giou;
        }
        __syncthreads();
    }
}

extern "C" void kernel_launch(void* const* d_in, const int* in_sizes, int n_in,
                              void* d_out, int out_size, void* d_ws, size_t ws_size,
                              hipStream_t stream) {
    const float* logits = (const float*)d_in[0];
    const float* boxes  = (const float*)d_in[1];
    const int*   tids   = (const int*)d_in[2];
    const float* tboxes = (const float*)d_in[3];
    float* out = (float*)d_out;

    const int BN = in_sizes[1] / 4;       // 14400
    const int NC = in_sizes[0] / BN;      // 91
    const int NT = in_sizes[2];           // 960

    if (NC == 91 && NT == 960 && BN % 4 == 0) {
        const int grid = BN / 4;          // 3600
        matcher_kernel_s<91, 960><<<grid, THREADS, 0, stream>>>(
            logits, boxes, tids, tboxes, out);
    } else {
        const int grid = (BN + GROWS - 1) / GROWS;
        const size_t shmem = (size_t)GROWS * NC * sizeof(float);
        matcher_kernel_g<<<grid, THREADS, shmem, stream>>>(
            logits, boxes, tids, tboxes, out, BN, NC, NT);
    }
}

// Round 8
// 24.830 us; speedup vs baseline: 1.1386x; 1.1386x over previous
//
#include <hip/hip_runtime.h>
#include <math.h>

// HungarianMatcher cost matrix:
//   C[i,j] = 5*L1(pred_box_i, tgt_box_j) + 2*focal(tgt class j) - 2*GIoU
// Shapes: pred_logits [BN,NC], pred_boxes [BN,4], tgt_ids [NT], tgt_bbox [NT,4]
// BN=16*900=14400, NC=91, NT=960. Output [BN,NT] fp32.
//
// R8: ROWS=8 (amortize fixed per-wave prologue over 32 el/thread), no VGPR cap,
// class table [c*9+r] (stride 9 coprime 32 -> conflict-free random gathers),
// folded formula: C = 5*l1 + tbl[c] - 2*(inter*carea + uni^2)/(uni*carea)
// where tbl[c] = 2*focal + 2  (the GIoU "+2" baked into the table).

#define ALPHA_F   0.25f
#define COST_CLS  2.0f
#define COST_BBOX 5.0f
#define COST_GIOU 2.0f
#define EPS_F     1e-8f

constexpr int THREADS = 256;

// ---------------------- specialized kernel (ROWS = 8) -----------------------
template<int NC, int NT>
__global__ __launch_bounds__(THREADS) void matcher_kernel_s(
    const float* __restrict__ logits,   // [BN, NC]
    const float* __restrict__ boxes,    // [BN, 4] cxcywh
    const int*   __restrict__ tids,     // [NT]
    const float* __restrict__ tboxes,   // [NT, 4] cxcywh
    float*       __restrict__ out)      // [BN, NT]
{
    constexpr int ROWS = 8;
    constexpr int JPT  = 4;                   // contiguous targets per thread
    constexpr int NJT  = NT / JPT;            // 240 active threads
    constexpr int NTAB = ROWS * NC;           // 728 table entries
    constexpr int LPT  = (NTAB + THREADS - 1) / THREADS;   // 3
    constexpr int CSTR = 9;                   // class stride (coprime with 32)

    __shared__ float s_cls[NC * CSTR];        // [class][8 rows+pad], 3.2 KB

    const int tid  = threadIdx.x;
    const int row0 = blockIdx.x * ROWS;
    const bool active = tid < NJT;

    // ---- issue logits loads first (feed the transcendental table chain) ----
    const float* __restrict__ lg = logits + (size_t)row0 * NC;
    float lv[LPT];
    #pragma unroll
    for (int i = 0; i < LPT; ++i) {
        const int t = tid + i * THREADS;
        lv[i] = (t < NTAB) ? lg[t] : 0.0f;
    }

    // ---- this thread's 4 targets: derived, row-invariant registers ----
    float tcx[JPT], tcy[JPT], tw[JPT], th[JPT];
    float tx0[JPT], tx1[JPT], ty0[JPT], ty1[JPT], tarea[JPT];
    const float* cp[JPT];
    if (active) {
        const int4 tv = reinterpret_cast<const int4*>(tids)[tid];
        const int ic[JPT] = {tv.x, tv.y, tv.z, tv.w};
        #pragma unroll
        for (int k = 0; k < JPT; ++k) {
            const float4 b = reinterpret_cast<const float4*>(tboxes)[tid * JPT + k];
            tcx[k] = b.x; tcy[k] = b.y; tw[k] = b.z; th[k] = b.w;
            const float hw = 0.5f * b.z, hh = 0.5f * b.w;
            tx0[k] = b.x - hw;  tx1[k] = b.x + hw;
            ty0[k] = b.y - hh;  ty1[k] = b.y + hh;
            tarea[k] = b.z * b.w;
            cp[k] = s_cls + ic[k] * CSTR;
        }
    } else {
        #pragma unroll
        for (int k = 0; k < JPT; ++k) {
            tcx[k]=tcy[k]=tw[k]=th[k]=tx0[k]=tx1[k]=ty0[k]=ty1[k]=tarea[k]=0.f;
            cp[k] = s_cls;
        }
    }

    // ---- focal class table: s_cls[c*9 + r] = 2*(pos-neg) + 2 ----
    #pragma unroll
    for (int i = 0; i < LPT; ++i) {
        const int t = tid + i * THREADS;
        if (t < NTAB) {
            const float x  = lv[i];
            const float p  = 1.0f / (1.0f + __expf(-x));
            const float om = 1.0f - p;
            const float neg = (1.0f - ALPHA_F) * p * p * (-__logf(om + EPS_F));
            const float pos = ALPHA_F * om * om        * (-__logf(p  + EPS_F));
            const int r = t / NC, c = t - r * NC;
            s_cls[c * CSTR + r] = COST_CLS * (pos - neg) + COST_GIOU;
        }
    }
    __syncthreads();   // the only barrier

    if (!active) return;

    float* __restrict__ optr = out + (size_t)row0 * NT + tid * JPT;
    #pragma unroll
    for (int r = 0; r < ROWS; ++r) {
        // block-uniform pred box (scalar-load path)
        const float4 pb = reinterpret_cast<const float4*>(boxes)[row0 + r];
        const float px0 = pb.x - 0.5f * pb.z, py0 = pb.y - 0.5f * pb.w;
        const float px1 = pb.x + 0.5f * pb.z, py1 = pb.y + 0.5f * pb.w;
        const float parea = pb.z * pb.w;

        float rv[JPT];
        #pragma unroll
        for (int k = 0; k < JPT; ++k) {
            // class gather: ds_read_b32 with compile-time offset, no addr math
            const float ctab = cp[k][r];
            // L1 in cxcywh space (abs folds into VOP3 src modifiers)
            const float l1 = (fabsf(pb.x - tcx[k]) + fabsf(pb.y - tcy[k]))
                           + (fabsf(pb.z - tw[k])  + fabsf(pb.w - th[k]));
            // raw intersection extents (feed enclosing box too)
            const float iwr = fminf(px1, tx1[k]) - fmaxf(px0, tx0[k]);
            const float ihr = fminf(py1, ty1[k]) - fmaxf(py0, ty0[k]);
            const float inter = fmaxf(iwr, 0.0f) * fmaxf(ihr, 0.0f);
            const float uni = (parea + tarea[k]) - inter;
            // enclosing box via identity: cw = pw + tw - iwr
            const float cw = (pb.z + tw[k]) - iwr;
            const float ch = (pb.w + th[k]) - ihr;
            const float carea = cw * ch;
            // C = 5*l1 + ctab - 2*(inter*carea + uni^2)/(uni*carea)
            const float num  = fmaf(inter, carea, uni * uni);
            const float rcpd = __builtin_amdgcn_rcpf(uni * carea);
            const float base = fmaf(COST_BBOX, l1, ctab);
            rv[k] = fmaf(-2.0f * num, rcpd, base);
        }
        *reinterpret_cast<float4*>(optr) = make_float4(rv[0], rv[1], rv[2], rv[3]);
        optr += NT;
    }
}

// ----------------------------- generic fallback -----------------------------
constexpr int GROWS = 8;
__global__ __launch_bounds__(THREADS) void matcher_kernel_g(
    const float* __restrict__ logits, const float* __restrict__ boxes,
    const int* __restrict__ tids, const float* __restrict__ tboxes,
    float* __restrict__ out, int BN, int NC, int NT)
{
    extern __shared__ float s_cls_g[];
    const int tid  = threadIdx.x;
    const int row0 = blockIdx.x * GROWS;
    const int nrows = (BN - row0 < GROWS) ? (BN - row0) : GROWS;

    for (int t = tid; t < nrows * NC; t += THREADS) {
        const int r = t / NC, c = t - r * NC;
        const float x  = logits[(size_t)(row0 + r) * NC + c];
        const float p  = 1.0f / (1.0f + expf(-x));
        const float om = 1.0f - p;
        const float neg = (1.0f - ALPHA_F) * p * p * (-logf(om + EPS_F));
        const float pos = ALPHA_F * om * om        * (-logf(p + EPS_F));
        s_cls_g[r * NC + c] = pos - neg;
    }
    __syncthreads();

    for (int r = 0; r < nrows; ++r) {
        const int row = row0 + r;
        const float4 pb = reinterpret_cast<const float4*>(boxes)[row];
        const float px0 = pb.x - 0.5f * pb.z, py0 = pb.y - 0.5f * pb.w;
        const float px1 = pb.x + 0.5f * pb.z, py1 = pb.y + 0.5f * pb.w;
        const float parea = pb.z * pb.w;
        for (int j = tid; j < NT; j += THREADS) {
            const float4 b = reinterpret_cast<const float4*>(tboxes)[j];
            const float bx0 = b.x - 0.5f * b.z, by0 = b.y - 0.5f * b.w;
            const float bx1 = b.x + 0.5f * b.z, by1 = b.y + 0.5f * b.w;
            const float l1 = fabsf(pb.x - b.x) + fabsf(pb.y - b.y)
                           + fabsf(pb.z - b.z) + fabsf(pb.w - b.w);
            const float iw = fmaxf(fminf(px1, bx1) - fmaxf(px0, bx0), 0.0f);
            const float ih = fmaxf(fminf(py1, by1) - fmaxf(py0, by0), 0.0f);
            const float inter = iw * ih;
            const float uni = parea + b.z * b.w - inter;
            const float iou = inter / uni;
            const float cw = fmaxf(px1, bx1) - fminf(px0, bx0);
            const float ch = fmaxf(py1, by1) - fminf(py0, by0);
            const float carea = cw * ch;
            const float giou = iou - (carea - uni) / carea;
            const float ccls = s_cls_g[r * NC + tids[j]];
            out[(size_t)row * NT + j] = COST_BBOX * l1 + COST_CLS * ccls - COST_GIOU * giou;
        }
        __syncthreads();
    }
}

extern "C" void kernel_launch(void* const* d_in, const int* in_sizes, int n_in,
                              void* d_out, int out_size, void* d_ws, size_t ws_size,
                              hipStream_t stream) {
    const float* logits = (const float*)d_in[0];
    const float* boxes  = (const float*)d_in[1];
    const int*   tids   = (const int*)d_in[2];
    const float* tboxes = (const float*)d_in[3];
    float* out = (float*)d_out;

    const int BN = in_sizes[1] / 4;       // 14400
    const int NC = in_sizes[0] / BN;      // 91
    const int NT = in_sizes[2];           // 960

    if (NC == 91 && NT == 960 && BN % 8 == 0) {
        const int grid = BN / 8;          // 1800
        matcher_kernel_s<91, 960><<<grid, THREADS, 0, stream>>>(
            logits, boxes, tids, tboxes, out);
    } else {
        const int grid = (BN + GROWS - 1) / GROWS;
        const size_t shmem = (size_t)GROWS * NC * sizeof(float);
        matcher_kernel_g<<<grid, THREADS, shmem, stream>>>(
            logits, boxes, tids, tboxes, out, BN, NC, NT);
    }
}

// Round 10
// 20.962 us; speedup vs baseline: 1.3487x; 1.1845x over previous
//
#include <hip/hip_runtime.h>
#include <math.h>

// HungarianMatcher cost matrix:
//   C[i,j] = 5*L1(pred_box_i, tgt_box_j) + 2*focal(tgt class j) - 2*GIoU
// Shapes: pred_logits [BN,NC], pred_boxes [BN,4], tgt_ids [NT], tgt_bbox [NT,4]
// BN=16*900=14400, NC=91, NT=960. Output [BN,NT] fp32.
//
// R9b: ROWS=2, grid=7200 -> 28 block-slots/CU (deep queue hides per-block
// prologue latency + shrinks tail to 3.5%). Table work per block = 182 chains
// (<=1 per thread, chip-total unchanged). Class costs prefetched to registers
// after the single barrier; nontemporal stores via clang ext_vector (float4
// HIP_vector_type is rejected by __builtin_nontemporal_store).

#define ALPHA_F   0.25f
#define COST_CLS  2.0f
#define COST_BBOX 5.0f
#define COST_GIOU 2.0f
#define EPS_F     1e-8f

constexpr int THREADS = 256;

typedef float vfloat4 __attribute__((ext_vector_type(4)));

// ---------------------- specialized kernel (ROWS = 2) -----------------------
template<int NC, int NT>
__global__ __launch_bounds__(THREADS) void matcher_kernel_s(
    const float* __restrict__ logits,   // [BN, NC]
    const float* __restrict__ boxes,    // [BN, 4] cxcywh
    const int*   __restrict__ tids,     // [NT]
    const float* __restrict__ tboxes,   // [NT, 4] cxcywh
    float*       __restrict__ out)      // [BN, NT]
{
    constexpr int ROWS = 2;
    constexpr int JPT  = 4;                   // contiguous targets per thread
    constexpr int NJT  = NT / JPT;            // 240 active threads
    constexpr int NTAB = ROWS * NC;           // 182 table entries (<= THREADS)
    constexpr int CSTR = 3;                   // class stride (coprime with 32)

    __shared__ float s_cls[NC * CSTR];        // ~1.1 KB

    const int tid  = threadIdx.x;
    const int row0 = blockIdx.x * ROWS;
    const bool active = tid < NJT;

    // ---- issue the logit load first (head of the transcendental chain) ----
    float x = 0.0f;
    if (tid < NTAB)
        x = logits[(size_t)row0 * NC + tid];

    // ---- this thread's 4 targets: raw cxcywh + class ids ----
    float4 tb[JPT];
    int ic[JPT] = {0, 0, 0, 0};
    if (active) {
        const int4 tv = reinterpret_cast<const int4*>(tids)[tid];
        ic[0] = tv.x; ic[1] = tv.y; ic[2] = tv.z; ic[3] = tv.w;
        #pragma unroll
        for (int k = 0; k < JPT; ++k)
            tb[k] = reinterpret_cast<const float4*>(tboxes)[tid * JPT + k];
    } else {
        #pragma unroll
        for (int k = 0; k < JPT; ++k) tb[k] = make_float4(0.f, 0.f, 0.f, 0.f);
    }

    // ---- focal class table: s_cls[c*3 + r] = 2*(pos-neg) + 2, one chain/thread ----
    if (tid < NTAB) {
        const float p  = 1.0f / (1.0f + __expf(-x));
        const float om = 1.0f - p;
        const float neg = (1.0f - ALPHA_F) * p * p * (-__logf(om + EPS_F));
        const float pos = ALPHA_F * om * om        * (-__logf(p  + EPS_F));
        const int r = (tid >= NC) ? 1 : 0;
        const int c = tid - (r ? NC : 0);
        s_cls[c * CSTR + r] = COST_CLS * (pos - neg) + COST_GIOU;
    }
    __syncthreads();   // the only barrier

    if (!active) return;

    // ---- prefetch both rows' class costs to registers (8x ds_read_b32) ----
    float cc0[JPT], cc1[JPT];
    #pragma unroll
    for (int k = 0; k < JPT; ++k) {
        const float* cp = s_cls + ic[k] * CSTR;
        cc0[k] = cp[0];
        cc1[k] = cp[1];
    }

    float* __restrict__ optr = out + (size_t)row0 * NT + tid * JPT;
    #pragma unroll
    for (int r = 0; r < ROWS; ++r) {
        // block-uniform pred box (scalar-load path)
        const float4 pb = reinterpret_cast<const float4*>(boxes)[row0 + r];
        const float px0 = pb.x - 0.5f * pb.z, py0 = pb.y - 0.5f * pb.w;
        const float px1 = pb.x + 0.5f * pb.z, py1 = pb.y + 0.5f * pb.w;
        const float parea = pb.z * pb.w;

        float rv[JPT];
        #pragma unroll
        for (int k = 0; k < JPT; ++k) {
            const float4 t = tb[k];
            const float hw = 0.5f * t.z, hh = 0.5f * t.w;
            const float tx0 = t.x - hw, tx1 = t.x + hw;
            const float ty0 = t.y - hh, ty1 = t.y + hh;
            const float tarea = t.z * t.w;
            // L1 in cxcywh space (abs folds into VOP3 src modifiers)
            const float l1 = (fabsf(pb.x - t.x) + fabsf(pb.y - t.y))
                           + (fabsf(pb.z - t.z) + fabsf(pb.w - t.w));
            // raw intersection extents (feed enclosing box too)
            const float iwr = fminf(px1, tx1) - fmaxf(px0, tx0);
            const float ihr = fminf(py1, ty1) - fmaxf(py0, ty0);
            const float inter = fmaxf(iwr, 0.0f) * fmaxf(ihr, 0.0f);
            const float uni = (parea + tarea) - inter;
            // enclosing box via identity: cw = pw + tw - iwr
            const float cw = (pb.z + t.z) - iwr;
            const float ch = (pb.w + t.w) - ihr;
            const float carea = cw * ch;
            // C = 5*l1 + tbl[c] - 2*(inter*carea + uni^2)/(uni*carea)
            const float num  = fmaf(inter, carea, uni * uni);
            const float rcpd = __builtin_amdgcn_rcpf(uni * carea);
            const float ctab = (r == 0) ? cc0[k] : cc1[k];
            const float base = fmaf(COST_BBOX, l1, ctab);
            rv[k] = fmaf(-2.0f * num, rcpd, base);
        }
        vfloat4 v;
        v.x = rv[0]; v.y = rv[1]; v.z = rv[2]; v.w = rv[3];
        __builtin_nontemporal_store(v, reinterpret_cast<vfloat4*>(optr));
        optr += NT;
    }
}

// ----------------------------- generic fallback -----------------------------
constexpr int GROWS = 8;
__global__ __launch_bounds__(THREADS) void matcher_kernel_g(
    const float* __restrict__ logits, const float* __restrict__ boxes,
    const int* __restrict__ tids, const float* __restrict__ tboxes,
    float* __restrict__ out, int BN, int NC, int NT)
{
    extern __shared__ float s_cls_g[];
    const int tid  = threadIdx.x;
    const int row0 = blockIdx.x * GROWS;
    const int nrows = (BN - row0 < GROWS) ? (BN - row0) : GROWS;

    for (int t = tid; t < nrows * NC; t += THREADS) {
        const int r = t / NC, c = t - r * NC;
        const float x  = logits[(size_t)(row0 + r) * NC + c];
        const float p  = 1.0f / (1.0f + expf(-x));
        const float om = 1.0f - p;
        const float neg = (1.0f - ALPHA_F) * p * p * (-logf(om + EPS_F));
        const float pos = ALPHA_F * om * om        * (-logf(p + EPS_F));
        s_cls_g[r * NC + c] = pos - neg;
    }
    __syncthreads();

    for (int r = 0; r < nrows; ++r) {
        const int row = row0 + r;
        const float4 pb = reinterpret_cast<const float4*>(boxes)[row];
        const float px0 = pb.x - 0.5f * pb.z, py0 = pb.y - 0.5f * pb.w;
        const float px1 = pb.x + 0.5f * pb.z, py1 = pb.y + 0.5f * pb.w;
        const float parea = pb.z * pb.w;
        for (int j = tid; j < NT; j += THREADS) {
            const float4 b = reinterpret_cast<const float4*>(tboxes)[j];
            const float bx0 = b.x - 0.5f * b.z, by0 = b.y - 0.5f * b.w;
            const float bx1 = b.x + 0.5f * b.z, by1 = b.y + 0.5f * b.w;
            const float l1 = fabsf(pb.x - b.x) + fabsf(pb.y - b.y)
                           + fabsf(pb.z - b.z) + fabsf(pb.w - b.w);
            const float iw = fmaxf(fminf(px1, bx1) - fmaxf(px0, bx0), 0.0f);
            const float ih = fmaxf(fminf(py1, by1) - fmaxf(py0, by0), 0.0f);
            const float inter = iw * ih;
            const float uni = parea + b.z * b.w - inter;
            const float iou = inter / uni;
            const float cw = fmaxf(px1, bx1) - fminf(px0, bx0);
            const float ch = fmaxf(py1, by1) - fminf(py0, by0);
            const float carea = cw * ch;
            const float giou = iou - (carea - uni) / carea;
            const float ccls = s_cls_g[r * NC + tids[j]];
            out[(size_t)row * NT + j] = COST_BBOX * l1 + COST_CLS * ccls - COST_GIOU * giou;
        }
        __syncthreads();
    }
}

extern "C" void kernel_launch(void* const* d_in, const int* in_sizes, int n_in,
                              void* d_out, int out_size, void* d_ws, size_t ws_size,
                              hipStream_t stream) {
    const float* logits = (const float*)d_in[0];
    const float* boxes  = (const float*)d_in[1];
    const int*   tids   = (const int*)d_in[2];
    const float* tboxes = (const float*)d_in[3];
    float* out = (float*)d_out;

    const int BN = in_sizes[1] / 4;       // 14400
    const int NC = in_sizes[0] / BN;      // 91
    const int NT = in_sizes[2];           // 960

    if (NC == 91 && NT == 960 && BN % 2 == 0) {
        const int grid = BN / 2;          // 7200
        matcher_kernel_s<91, 960><<<grid, THREADS, 0, stream>>>(
            logits, boxes, tids, tboxes, out);
    } else {
        const int grid = (BN + GROWS - 1) / GROWS;
        const size_t shmem = (size_t)GROWS * NC * sizeof(float);
        matcher_kernel_g<<<grid, THREADS, shmem, stream>>>(
            logits, boxes, tids, tboxes, out, BN, NC, NT);
    }
}